// Round 16
// baseline (143.041 us; speedup 1.0000x reference)
//
#include <hip/hip_runtime.h>
#include <hip/hip_bf16.h>

#define NB 8
#define SEQ 2048
#define DM 1024
#define AD 64
#define NROWS (NB * SEQ)          // 16384

// exp(s/32) = 2^(s * 0.03125 * log2(e));  log2(e)/32 = 0.045084220
#define SCL2 0.04508422f

typedef __attribute__((ext_vector_type(8))) short short8;
typedef __attribute__((ext_vector_type(4))) float f32x4;

static __device__ __forceinline__ unsigned short f2bf(float f) {
    unsigned int u = __float_as_uint(f);
    u += 0x7FFFu + ((u >> 16) & 1u);
    return (unsigned short)(u >> 16);
}

static __device__ __forceinline__ f32x4 mfma16(short8 a, short8 b, f32x4 c) {
    return __builtin_amdgcn_mfma_f32_16x16x32_bf16(a, b, c, 0, 0, 0);
}

static __device__ __forceinline__ short8 pack8(float4 a, float4 b) {
    short8 r;
    r[0] = (short)f2bf(a.x); r[1] = (short)f2bf(a.y);
    r[2] = (short)f2bf(a.z); r[3] = (short)f2bf(a.w);
    r[4] = (short)f2bf(b.x); r[5] = (short)f2bf(b.y);
    r[6] = (short)f2bf(b.z); r[7] = (short)f2bf(b.w);
    return r;
}

static __device__ __forceinline__ short8 pack8v(f32x4 a, f32x4 b) {
    short8 r;
    r[0] = (short)f2bf(a[0]); r[1] = (short)f2bf(a[1]);
    r[2] = (short)f2bf(a[2]); r[3] = (short)f2bf(a[3]);
    r[4] = (short)f2bf(b[0]); r[5] = (short)f2bf(b[1]);
    r[6] = (short)f2bf(b[2]); r[7] = (short)f2bf(b[3]);
    return r;
}

// ---------------------------------------------------------------------------
// Kernel 0: transpose + convert W (fp32 [1024][64]) -> wT bf16 [3][64][1024]
// ---------------------------------------------------------------------------
__global__ __launch_bounds__(256) void wT_kernel(
    const float* __restrict__ Wq, const float* __restrict__ Wk,
    const float* __restrict__ Wv, unsigned short* __restrict__ wT) {
    int p = blockIdx.y;
    int k0 = blockIdx.x * 64;
    const float* W = (p == 0) ? Wq : (p == 1) ? Wk : Wv;
    __shared__ unsigned short tl[64][72];
    int t = threadIdx.x;
    int c = t & 63;
    int r0 = t >> 6;
    for (int i = 0; i < 16; i++) {
        int k = r0 + i * 4;
        tl[c][k] = f2bf(W[(size_t)(k0 + k) * AD + c]);
    }
    __syncthreads();
    for (int i = 0; i < 16; i++) {
        int a = r0 + i * 4;
        wT[((size_t)p * AD + a) * DM + k0 + c] = tl[a][c];
    }
}

// ---------------------------------------------------------------------------
// Kernel 1: projection X[16384][1024] @ W[1024][64] + b -> bf16.
// SINGLE-WAVE WGs + TWO K-STREAMS. Model from 12 measured variants: proj is
// per-wave latency-serialized (prefetch distance 1 covers ~200cy of ~900+cy
// latency) and capped at ~12 waves/CU (grid 768 = 3 WG/CU). Fixes:
//  - grid (1024,3) = 3072 one-wave WGs -> up to 16 WG/CU = 16 waves/CU.
//  - each wave runs chunks i and i+8 as independent streams (separate
//    accumulators, merged at end): both prefetch bursts issue back-to-back,
//    ONE wait per iteration -> 8 stalls instead of 16, 2x outstanding bytes.
// Register-direct A-frags (r4-style), no staging LDS, no barriers; 3 KB LDS
// only for the p==2 epilogue transpose.
// ---------------------------------------------------------------------------
__global__ __launch_bounds__(64) void proj_kernel(
    const float* __restrict__ q_in, const float* __restrict__ k_in,
    const float* __restrict__ v_in, const float* __restrict__ bq,
    const float* __restrict__ bk, const float* __restrict__ bv,
    const unsigned short* __restrict__ wT,
    unsigned short* __restrict__ q_out, unsigned short* __restrict__ k_out,
    unsigned short* __restrict__ vT_out) {
    int p = blockIdx.y;
    int rbase = blockIdx.x * 16;
    const float* X = (p == 0) ? q_in : (p == 1) ? k_in : v_in;
    const float* bias = (p == 0) ? bq : (p == 1) ? bk : bv;
    const unsigned short* wTp = wT + (size_t)p * AD * DM;

    __shared__ unsigned short sc[64][24];  // p==2 epilogue transpose only

    int lane = threadIdx.x & 63;
    int arow = lane & 15;
    int agrp = lane >> 4;

    const float* XrA = X + (size_t)(rbase + arow) * DM + agrp * 8;        // k 0..511
    const float* XrB = XrA + 512;                                         // k 512..1023

    f32x4 accA[4], accB[4];
#pragma unroll
    for (int ct = 0; ct < 4; ct++) {
        accA[ct] = (f32x4){0.f, 0.f, 0.f, 0.f};
        accB[ct] = (f32x4){0.f, 0.f, 0.f, 0.f};
    }

    float4 pa0 = *reinterpret_cast<const float4*>(XrA + 0);
    float4 pa1 = *reinterpret_cast<const float4*>(XrA + 4);
    float4 pa2 = *reinterpret_cast<const float4*>(XrA + 32);
    float4 pa3 = *reinterpret_cast<const float4*>(XrA + 36);
    float4 pb0 = *reinterpret_cast<const float4*>(XrB + 0);
    float4 pb1 = *reinterpret_cast<const float4*>(XrB + 4);
    float4 pb2 = *reinterpret_cast<const float4*>(XrB + 32);
    float4 pb3 = *reinterpret_cast<const float4*>(XrB + 36);

#pragma unroll
    for (int i = 0; i < 8; ++i) {
        int kbA = i * 64;
        int kbB = 512 + i * 64;
        // consume both streams' prefetched data into bf16 frags
        short8 afA0 = pack8(pa0, pa1);
        short8 afA1 = pack8(pa2, pa3);
        short8 afB0 = pack8(pb0, pb1);
        short8 afB1 = pack8(pb2, pb3);
        // issue next iteration's loads for BOTH streams back-to-back
        if (i < 7) {
            const float* XnA = XrA + (i + 1) * 64;
            pa0 = *reinterpret_cast<const float4*>(XnA + 0);
            pa1 = *reinterpret_cast<const float4*>(XnA + 4);
            pa2 = *reinterpret_cast<const float4*>(XnA + 32);
            pa3 = *reinterpret_cast<const float4*>(XnA + 36);
            const float* XnB = XrB + (i + 1) * 64;
            pb0 = *reinterpret_cast<const float4*>(XnB + 0);
            pb1 = *reinterpret_cast<const float4*>(XnB + 4);
            pb2 = *reinterpret_cast<const float4*>(XnB + 32);
            pb3 = *reinterpret_cast<const float4*>(XnB + 36);
        }
        // 16 MFMAs (8 per stream); wT is L2-resident
#pragma unroll
        for (int ct = 0; ct < 4; ct++) {
            const unsigned short* wrA = wTp + (size_t)(ct * 16 + arow) * DM + kbA;
            accA[ct] = mfma16(afA0, *reinterpret_cast<const short8*>(wrA + agrp * 8), accA[ct]);
            accA[ct] = mfma16(afA1, *reinterpret_cast<const short8*>(wrA + 32 + agrp * 8), accA[ct]);
            const unsigned short* wrB = wTp + (size_t)(ct * 16 + arow) * DM + kbB;
            accB[ct] = mfma16(afB0, *reinterpret_cast<const short8*>(wrB + agrp * 8), accB[ct]);
            accB[ct] = mfma16(afB1, *reinterpret_cast<const short8*>(wrB + 32 + agrp * 8), accB[ct]);
        }
    }

    if (p < 2) {
        unsigned short* outp = (p == 0) ? q_out : k_out;
#pragma unroll
        for (int ct = 0; ct < 4; ct++) {
            int a = ct * 16 + arow;
            float bv_ = bias[a];
#pragma unroll
            for (int r = 0; r < 4; r++) {
                int row = rbase + agrp * 4 + r;
                float v = accA[ct][r] + accB[ct][r];
                outp[(size_t)row * AD + a] = f2bf(v + bv_);
            }
        }
    } else {
        // wave-internal transpose via small LDS, then write vT[b][a][s]
#pragma unroll
        for (int ct = 0; ct < 4; ct++) {
            int a = ct * 16 + arow;
            float bv_ = bias[a];
#pragma unroll
            for (int r = 0; r < 4; r++) {
                float v = accA[ct][r] + accB[ct][r];
                sc[a][agrp * 4 + r] = f2bf(v + bv_);
            }
        }
        __syncthreads();
        int bidx = rbase >> 11;
        int sbase = rbase & 2047;
        unsigned short* vrow = vT_out + ((size_t)bidx * AD + lane) * SEQ + sbase;
#pragma unroll
        for (int i = 0; i < 4; i++) {
            uint2 v = *reinterpret_cast<const uint2*>(&sc[lane][i * 4]);
            *reinterpret_cast<uint2*>(vrow + i * 4) = v;
        }
    }
}

// ---------------------------------------------------------------------------
// Kernel 2a: partial exp-sums, 32 q-rows per block (two A-frag pairs share
// every K-fragment load). grid 2048 = (qt 64, sp 4, b 8), b in low 3 bits
// (XCD pin). block 128 = 2 waves; wave w covers keys [sp*512 + w*256, +256).
// ---------------------------------------------------------------------------
__global__ __launch_bounds__(128, 6) void sum_kernel(
    const unsigned short* __restrict__ qb, const unsigned short* __restrict__ kb,
    float* __restrict__ rowsumpart) {
    int blk = blockIdx.x;
    int b = blk & 7;
    int sp = (blk >> 3) & 3;
    int qbase = (blk >> 5) * 32;

    __shared__ float wsum[2][32];

    int t = threadIdx.x;
    int lane = t & 63;
    int w = t >> 6;
    int arow = lane & 15;
    int agrp = lane >> 4;

    const unsigned short* qrow = qb + ((size_t)b * SEQ + qbase) * AD;
    short8 qf0a = *reinterpret_cast<const short8*>(qrow + (size_t)arow * AD + agrp * 8);
    short8 qf1a = *reinterpret_cast<const short8*>(qrow + (size_t)arow * AD + 32 + agrp * 8);
    short8 qf0b = *reinterpret_cast<const short8*>(qrow + (size_t)(16 + arow) * AD + agrp * 8);
    short8 qf1b = *reinterpret_cast<const short8*>(qrow + (size_t)(16 + arow) * AD + 32 + agrp * 8);
    const unsigned short* kbp = kb + (size_t)b * SEQ * AD;

    int keybase = sp * 512 + w * 256;
    float sA[4] = {0.f, 0.f, 0.f, 0.f};
    float sB[4] = {0.f, 0.f, 0.f, 0.f};
    for (int kt = 0; kt < 16; ++kt) {
        int key0 = keybase + kt * 16;
        const unsigned short* krow = kbp + (size_t)(key0 + arow) * AD;
        short8 kf0 = *reinterpret_cast<const short8*>(krow + agrp * 8);
        short8 kf1 = *reinterpret_cast<const short8*>(krow + 32 + agrp * 8);
        f32x4 aA = (f32x4){0.f, 0.f, 0.f, 0.f};
        aA = mfma16(qf0a, kf0, aA);
        aA = mfma16(qf1a, kf1, aA);
        f32x4 aB = (f32x4){0.f, 0.f, 0.f, 0.f};
        aB = mfma16(qf0b, kf0, aB);
        aB = mfma16(qf1b, kf1, aB);
#pragma unroll
        for (int r = 0; r < 4; r++) {
            sA[r] += __builtin_amdgcn_exp2f(aA[r] * SCL2);
            sB[r] += __builtin_amdgcn_exp2f(aB[r] * SCL2);
        }
    }
#pragma unroll
    for (int r = 0; r < 4; r++) {
#pragma unroll
        for (int off = 1; off < 16; off <<= 1) {
            sA[r] += __shfl_xor(sA[r], off);
            sB[r] += __shfl_xor(sB[r], off);
        }
    }
    if (arow == 0) {
#pragma unroll
        for (int r = 0; r < 4; r++) {
            wsum[w][agrp * 4 + r] = sA[r];
            wsum[w][16 + agrp * 4 + r] = sB[r];
        }
    }
    __syncthreads();
    if (t < 32)
        rowsumpart[(size_t)sp * NROWS + (size_t)b * SEQ + qbase + t] =
            wsum[0][t] + wsum[1][t];
}

// ---------------------------------------------------------------------------
// Kernel 2b: lr = -log2(sum of partials). (amdgcn logf IS log2.)
// ---------------------------------------------------------------------------
__global__ __launch_bounds__(256) void lr_kernel(
    const float* __restrict__ part, float* __restrict__ lr_g) {
    int i = blockIdx.x * 256 + threadIdx.x;
    float S = part[i] + part[NROWS + i] + part[2 * NROWS + i] + part[3 * NROWS + i];
    lr_g[i] = -__builtin_amdgcn_logf(S);
}

// ---------------------------------------------------------------------------
// Kernel 2c (MERGED attn2+ctx): normalize + write attn + PV + direct ctx.
// One WG = 32 q-rows x ALL 2048 keys: 8 waves, wave w covers keys
// [w*256,(w+1)*256). After PV, 8 wave-partials are reduced through LDS and
// ctx written directly. grid 512 = (qt 64, b 8), b in low 3 bits (XCD pin).
// block 512. LDS sf[8][32][68] = 70 KB -> 2 WG/CU (16 waves/CU).
// ---------------------------------------------------------------------------
__global__ __launch_bounds__(512, 2) void attn2_kernel(
    const unsigned short* __restrict__ qb, const unsigned short* __restrict__ kb,
    const unsigned short* __restrict__ vT, const float* __restrict__ lr_g,
    float* __restrict__ attn_out, float* __restrict__ ctx_out) {
    int blk = blockIdx.x;
    int b = blk & 7;
    int qbase = (blk >> 3) * 32;

    __shared__ float sf[8][32][68];
    __shared__ float lr_lds[32];

    int t = threadIdx.x;
    int lane = t & 63;
    int w = t >> 6;       // 0..7
    int arow = lane & 15;
    int agrp = lane >> 4;

    if (t < 32) lr_lds[t] = lr_g[(size_t)b * SEQ + qbase + t];

    const unsigned short* qrow = qb + ((size_t)b * SEQ + qbase) * AD;
    short8 qf0a = *reinterpret_cast<const short8*>(qrow + (size_t)arow * AD + agrp * 8);
    short8 qf1a = *reinterpret_cast<const short8*>(qrow + (size_t)arow * AD + 32 + agrp * 8);
    short8 qf0b = *reinterpret_cast<const short8*>(qrow + (size_t)(16 + arow) * AD + agrp * 8);
    short8 qf1b = *reinterpret_cast<const short8*>(qrow + (size_t)(16 + arow) * AD + 32 + agrp * 8);
    const unsigned short* kbp = kb + (size_t)b * SEQ * AD;
    const unsigned short* vTb = vT + (size_t)b * AD * SEQ;
    float* attn_b = attn_out + ((size_t)b * SEQ + qbase) * SEQ;
    __syncthreads();

    float lrA[4], lrB[4];
#pragma unroll
    for (int r = 0; r < 4; r++) {
        lrA[r] = lr_lds[agrp * 4 + r];
        lrB[r] = lr_lds[16 + agrp * 4 + r];
    }

    f32x4 caccA[4], caccB[4];
#pragma unroll
    for (int ct = 0; ct < 4; ct++) {
        caccA[ct] = (f32x4){0.f, 0.f, 0.f, 0.f};
        caccB[ct] = (f32x4){0.f, 0.f, 0.f, 0.f};
    }

    int keybase = w * 256;
    for (int g = 0; g < 4; ++g) {
        int key0b = keybase + g * 64;
#pragma unroll
        for (int kb4 = 0; kb4 < 4; ++kb4) {
            int k0 = key0b + kb4 * 16;
            const unsigned short* krow = kbp + (size_t)(k0 + arow) * AD;
            short8 kf0 = *reinterpret_cast<const short8*>(krow + agrp * 8);
            short8 kf1 = *reinterpret_cast<const short8*>(krow + 32 + agrp * 8);
            f32x4 aA = (f32x4){0.f, 0.f, 0.f, 0.f};
            aA = mfma16(qf0a, kf0, aA);
            aA = mfma16(qf1a, kf1, aA);
            f32x4 aB = (f32x4){0.f, 0.f, 0.f, 0.f};
            aB = mfma16(qf0b, kf0, aB);
            aB = mfma16(qf1b, kf1, aB);
#pragma unroll
            for (int r = 0; r < 4; r++) {
                sf[w][agrp * 4 + r][kb4 * 16 + arow] =
                    __builtin_amdgcn_exp2f(aA[r] * SCL2 + lrA[r]);
                sf[w][16 + agrp * 4 + r][kb4 * 16 + arow] =
                    __builtin_amdgcn_exp2f(aB[r] * SCL2 + lrB[r]);
            }
        }
        // coalesced attn stores: 32 rows x 64 keys, 16 B/lane per store
#pragma unroll
        for (int j = 0; j < 8; ++j) {
            int row = j * 4 + agrp;
            int c4 = arow * 4;
            f32x4 vv = *reinterpret_cast<const f32x4*>(&sf[w][row][c4]);
            __builtin_nontemporal_store(
                vv, reinterpret_cast<f32x4*>(&attn_b[(size_t)row * SEQ + key0b + c4]));
        }
        // PV: A-frags from sf (both q-groups), V-frag loaded once, used twice
#pragma unroll
        for (int ks = 0; ks < 2; ++ks) {
            f32x4 pa0 = *reinterpret_cast<const f32x4*>(&sf[w][arow][ks * 32 + agrp * 8]);
            f32x4 pa1 = *reinterpret_cast<const f32x4*>(&sf[w][arow][ks * 32 + agrp * 8 + 4]);
            short8 pfA = pack8v(pa0, pa1);
            f32x4 pb0 = *reinterpret_cast<const f32x4*>(&sf[w][16 + arow][ks * 32 + agrp * 8]);
            f32x4 pb1 = *reinterpret_cast<const f32x4*>(&sf[w][16 + arow][ks * 32 + agrp * 8 + 4]);
            short8 pfB = pack8v(pb0, pb1);
#pragma unroll
            for (int ct = 0; ct < 4; ct++) {
                const unsigned short* vr =
                    vTb + (size_t)(ct * 16 + arow) * SEQ + key0b + ks * 32 + agrp * 8;
                short8 vv = *reinterpret_cast<const short8*>(vr);
                caccA[ct] = mfma16(pfA, vv, caccA[ct]);
                caccB[ct] = mfma16(pfB, vv, caccB[ct]);
            }
        }
    }

    // ---- 8-wave ctx reduce via LDS, then direct ctx write ----
    __syncthreads();  // all waves done with their sf score slices
#pragma unroll
    for (int ct = 0; ct < 4; ct++)
#pragma unroll
        for (int r = 0; r < 4; r++) {
            sf[w][agrp * 4 + r][ct * 16 + arow] = caccA[ct][r];
            sf[w][16 + agrp * 4 + r][ct * 16 + arow] = caccB[ct][r];
        }
    __syncthreads();

    float* ctx_b = ctx_out + ((size_t)b * SEQ + qbase) * AD;
    for (int i = t; i < 32 * 64; i += 512) {
        int r = i >> 6, a = i & 63;
        float v = ((sf[0][r][a] + sf[1][r][a]) + (sf[2][r][a] + sf[3][r][a])) +
                  ((sf[4][r][a] + sf[5][r][a]) + (sf[6][r][a] + sf[7][r][a]));
        __builtin_nontemporal_store(v, &ctx_b[(size_t)r * AD + a]);
    }
}

// ---------------------------------------------------------------------------
extern "C" void kernel_launch(void* const* d_in, const int* in_sizes, int n_in,
                              void* d_out, int out_size, void* d_ws, size_t ws_size,
                              hipStream_t stream) {
    const float* q_in = (const float*)d_in[0];
    const float* k_in = (const float*)d_in[1];
    const float* v_in = (const float*)d_in[2];
    const float* Wq = (const float*)d_in[3];
    const float* bq = (const float*)d_in[4];
    const float* Wk = (const float*)d_in[5];
    const float* bk = (const float*)d_in[6];
    const float* Wv = (const float*)d_in[7];
    const float* bv = (const float*)d_in[8];

    char* ws = (char*)d_ws;
    unsigned short* q_bf = (unsigned short*)(ws);                    // 2 MB
    unsigned short* k_bf = (unsigned short*)(ws + (2u << 20));       // 2 MB
    unsigned short* vT   = (unsigned short*)(ws + (4u << 20));       // 2 MB
    unsigned short* wT   = (unsigned short*)(ws + (6u << 20));       // 384 KB
    float* rowsumpart    = (float*)(ws + (7u << 20));                // 256 KB
    float* lr_g          = (float*)(ws + (7u << 20) + (256u << 10)); // 64 KB

    float* ctx_out = (float*)d_out;
    float* attn_out = ctx_out + (size_t)NB * SEQ * AD;

    hipLaunchKernelGGL(wT_kernel, dim3(16, 3), dim3(256), 0, stream, Wq, Wk, Wv, wT);
    hipLaunchKernelGGL(proj_kernel, dim3(1024, 3), dim3(64), 0, stream,
                       q_in, k_in, v_in, bq, bk, bv, wT, q_bf, k_bf, vT);
    hipLaunchKernelGGL(sum_kernel, dim3(2048), dim3(128), 0, stream,
                       q_bf, k_bf, rowsumpart);
    hipLaunchKernelGGL(lr_kernel, dim3(64), dim3(256), 0, stream, rowsumpart, lr_g);
    hipLaunchKernelGGL(attn2_kernel, dim3(512), dim3(512), 0, stream,
                       q_bf, k_bf, vT, lr_g, attn_out, ctx_out);
}

// Round 17
// 132.695 us; speedup vs baseline: 1.0780x; 1.0780x over previous
//
#include <hip/hip_runtime.h>
#include <hip/hip_bf16.h>

#define NB 8
#define SEQ 2048
#define DM 1024
#define AD 64
#define NROWS (NB * SEQ)          // 16384

// exp(s/32) = 2^(s * 0.03125 * log2(e));  log2(e)/32 = 0.045084220
#define SCL2 0.04508422f

typedef __attribute__((ext_vector_type(8))) short short8;
typedef __attribute__((ext_vector_type(4))) float f32x4;

static __device__ __forceinline__ unsigned short f2bf(float f) {
    unsigned int u = __float_as_uint(f);
    u += 0x7FFFu + ((u >> 16) & 1u);
    return (unsigned short)(u >> 16);
}

static __device__ __forceinline__ f32x4 mfma16(short8 a, short8 b, f32x4 c) {
    return __builtin_amdgcn_mfma_f32_16x16x32_bf16(a, b, c, 0, 0, 0);
}

static __device__ __forceinline__ short8 pack8v(f32x4 a, f32x4 b) {
    short8 r;
    r[0] = (short)f2bf(a[0]); r[1] = (short)f2bf(a[1]);
    r[2] = (short)f2bf(a[2]); r[3] = (short)f2bf(a[3]);
    r[4] = (short)f2bf(b[0]); r[5] = (short)f2bf(b[1]);
    r[6] = (short)f2bf(b[2]); r[7] = (short)f2bf(b[3]);
    return r;
}

// ---------------------------------------------------------------------------
// Kernel 0: transpose + convert W (fp32 [1024][64]) -> wT bf16 [3][64][1024]
// ---------------------------------------------------------------------------
__global__ __launch_bounds__(256) void wT_kernel(
    const float* __restrict__ Wq, const float* __restrict__ Wk,
    const float* __restrict__ Wv, unsigned short* __restrict__ wT) {
    int p = blockIdx.y;
    int k0 = blockIdx.x * 64;
    const float* W = (p == 0) ? Wq : (p == 1) ? Wk : Wv;
    __shared__ unsigned short tl[64][72];
    int t = threadIdx.x;
    int c = t & 63;
    int r0 = t >> 6;
    for (int i = 0; i < 16; i++) {
        int k = r0 + i * 4;
        tl[c][k] = f2bf(W[(size_t)(k0 + k) * AD + c]);
    }
    __syncthreads();
    for (int i = 0; i < 16; i++) {
        int a = r0 + i * 4;
        wT[((size_t)p * AD + a) * DM + k0 + c] = tl[a][c];
    }
}

// ---------------------------------------------------------------------------
// Kernel 1: projection X[16384][1024] @ W[1024][64] + b -> bf16.
// r11 T14 pipeline (twice-reproduced best X path: 79 us) MINUS W-staging:
// W-fragments read directly from L2-hot wT in the compute phase (r4/r13
// proved direct-W pipelines fine; their deficit was the X path). Cuts LDS
// 53->35 KB => 4 WG/CU = 16 waves/CU (vs 3 WG/12 waves), removes 2 of 6
// staged loads, and shortens the pre-barrier critical path.
// grid (256, 3), block 256 (wave w owns rows w*16..w*16+15 of 64-row tile).
// ---------------------------------------------------------------------------
__global__ __launch_bounds__(256, 4) void proj_kernel(
    const float* __restrict__ q_in, const float* __restrict__ k_in,
    const float* __restrict__ v_in, const float* __restrict__ bq,
    const float* __restrict__ bk, const float* __restrict__ bv,
    const unsigned short* __restrict__ wT,
    unsigned short* __restrict__ q_out, unsigned short* __restrict__ k_out,
    unsigned short* __restrict__ vT_out) {
    int p = blockIdx.y;
    int rbase = blockIdx.x * 64;
    const float* X = (p == 0) ? q_in : (p == 1) ? k_in : v_in;
    const float* bias = (p == 0) ? bq : (p == 1) ? bk : bv;
    const unsigned short* wTp = wT + (size_t)p * AD * DM;

    __shared__ float xs[2][64][68];  // fp32 X chunk, pad 4

    int t = threadIdx.x;
    int lane = t & 63;
    int w = t >> 6;
    int arow = lane & 15;
    int agrp = lane >> 4;

    int srow = t >> 4;        // 0..15
    int scol = (t & 15) * 4;  // fp32 col

    const float* Xb = X + (size_t)rbase * DM;

    f32x4 acc[4];
#pragma unroll
    for (int ct = 0; ct < 4; ct++) acc[ct] = (f32x4){0.f, 0.f, 0.f, 0.f};

    float4 px0, px1, px2, px3;

    // prologue: load + write chunk 0
    px0 = *reinterpret_cast<const float4*>(&Xb[(size_t)(0 * 16 + srow) * DM + scol]);
    px1 = *reinterpret_cast<const float4*>(&Xb[(size_t)(1 * 16 + srow) * DM + scol]);
    px2 = *reinterpret_cast<const float4*>(&Xb[(size_t)(2 * 16 + srow) * DM + scol]);
    px3 = *reinterpret_cast<const float4*>(&Xb[(size_t)(3 * 16 + srow) * DM + scol]);
    *reinterpret_cast<float4*>(&xs[0][0 * 16 + srow][scol]) = px0;
    *reinterpret_cast<float4*>(&xs[0][1 * 16 + srow][scol]) = px1;
    *reinterpret_cast<float4*>(&xs[0][2 * 16 + srow][scol]) = px2;
    *reinterpret_cast<float4*>(&xs[0][3 * 16 + srow][scol]) = px3;
    __syncthreads();

    for (int c = 0; c < 16; ++c) {
        int bu = c & 1;
        if (c < 15) {
            int kb = (c + 1) * 64;
            px0 = *reinterpret_cast<const float4*>(&Xb[(size_t)(0 * 16 + srow) * DM + kb + scol]);
            px1 = *reinterpret_cast<const float4*>(&Xb[(size_t)(1 * 16 + srow) * DM + kb + scol]);
            px2 = *reinterpret_cast<const float4*>(&Xb[(size_t)(2 * 16 + srow) * DM + kb + scol]);
            px3 = *reinterpret_cast<const float4*>(&Xb[(size_t)(3 * 16 + srow) * DM + kb + scol]);
        }
        // ---- compute chunk c: A from LDS, B direct from L2-hot wT ----
        const float* xr = &xs[bu][w * 16 + arow][0];
        int kb0 = c * 64;
#pragma unroll
        for (int s = 0; s < 2; ++s) {
            f32x4 a0 = *reinterpret_cast<const f32x4*>(&xr[s * 32 + agrp * 8]);
            f32x4 a1 = *reinterpret_cast<const f32x4*>(&xr[s * 32 + agrp * 8 + 4]);
            short8 af = pack8v(a0, a1);
#pragma unroll
            for (int ct = 0; ct < 4; ++ct) {
                const unsigned short* wr =
                    wTp + (size_t)(ct * 16 + arow) * DM + kb0 + s * 32 + agrp * 8;
                acc[ct] = mfma16(af, *reinterpret_cast<const short8*>(wr), acc[ct]);
            }
        }
        // ---- write prefetched chunk c+1 (vmcnt wait lands here) ----
        if (c < 15) {
            int bo = bu ^ 1;
            *reinterpret_cast<float4*>(&xs[bo][0 * 16 + srow][scol]) = px0;
            *reinterpret_cast<float4*>(&xs[bo][1 * 16 + srow][scol]) = px1;
            *reinterpret_cast<float4*>(&xs[bo][2 * 16 + srow][scol]) = px2;
            *reinterpret_cast<float4*>(&xs[bo][3 * 16 + srow][scol]) = px3;
        }
        __syncthreads();
    }

    if (p < 2) {
        unsigned short* outp = (p == 0) ? q_out : k_out;
#pragma unroll
        for (int ct = 0; ct < 4; ct++) {
            int a = ct * 16 + arow;
            float bv_ = bias[a];
#pragma unroll
            for (int rr = 0; rr < 4; rr++) {
                int row = rbase + w * 16 + agrp * 4 + rr;
                outp[(size_t)row * AD + a] = f2bf(acc[ct][rr] + bv_);
            }
        }
    } else {
        // transpose via LDS scratch (reuse xs), then write vT[b][a][s]
        unsigned short* sc = (unsigned short*)&xs[0][0][0];  // [64][72]
#pragma unroll
        for (int ct = 0; ct < 4; ct++) {
            int a = ct * 16 + arow;
            float bv_ = bias[a];
#pragma unroll
            for (int rr = 0; rr < 4; rr++) {
                int row = w * 16 + agrp * 4 + rr;
                sc[a * 72 + row] = f2bf(acc[ct][rr] + bv_);
            }
        }
        __syncthreads();
        int bidx = rbase >> 11;
        int sbase = rbase & 2047;
        int rr = t & 63;
        for (int i = 0; i < 16; i++) {
            int a = (t >> 6) + i * 4;
            vT_out[((size_t)bidx * AD + a) * SEQ + sbase + rr] = sc[a * 72 + rr];
        }
    }
}

// ---------------------------------------------------------------------------
// Kernel 2a: partial exp-sums, 32 q-rows per block (two A-frag pairs share
// every K-fragment load). grid 2048 = (qt 64, sp 4, b 8), b in low 3 bits
// (XCD pin). block 128 = 2 waves; wave w covers keys [sp*512 + w*256, +256).
// ---------------------------------------------------------------------------
__global__ __launch_bounds__(128, 6) void sum_kernel(
    const unsigned short* __restrict__ qb, const unsigned short* __restrict__ kb,
    float* __restrict__ rowsumpart) {
    int blk = blockIdx.x;
    int b = blk & 7;
    int sp = (blk >> 3) & 3;
    int qbase = (blk >> 5) * 32;

    __shared__ float wsum[2][32];

    int t = threadIdx.x;
    int lane = t & 63;
    int w = t >> 6;
    int arow = lane & 15;
    int agrp = lane >> 4;

    const unsigned short* qrow = qb + ((size_t)b * SEQ + qbase) * AD;
    short8 qf0a = *reinterpret_cast<const short8*>(qrow + (size_t)arow * AD + agrp * 8);
    short8 qf1a = *reinterpret_cast<const short8*>(qrow + (size_t)arow * AD + 32 + agrp * 8);
    short8 qf0b = *reinterpret_cast<const short8*>(qrow + (size_t)(16 + arow) * AD + agrp * 8);
    short8 qf1b = *reinterpret_cast<const short8*>(qrow + (size_t)(16 + arow) * AD + 32 + agrp * 8);
    const unsigned short* kbp = kb + (size_t)b * SEQ * AD;

    int keybase = sp * 512 + w * 256;
    float sA[4] = {0.f, 0.f, 0.f, 0.f};
    float sB[4] = {0.f, 0.f, 0.f, 0.f};
    for (int kt = 0; kt < 16; ++kt) {
        int key0 = keybase + kt * 16;
        const unsigned short* krow = kbp + (size_t)(key0 + arow) * AD;
        short8 kf0 = *reinterpret_cast<const short8*>(krow + agrp * 8);
        short8 kf1 = *reinterpret_cast<const short8*>(krow + 32 + agrp * 8);
        f32x4 aA = (f32x4){0.f, 0.f, 0.f, 0.f};
        aA = mfma16(qf0a, kf0, aA);
        aA = mfma16(qf1a, kf1, aA);
        f32x4 aB = (f32x4){0.f, 0.f, 0.f, 0.f};
        aB = mfma16(qf0b, kf0, aB);
        aB = mfma16(qf1b, kf1, aB);
#pragma unroll
        for (int r = 0; r < 4; r++) {
            sA[r] += __builtin_amdgcn_exp2f(aA[r] * SCL2);
            sB[r] += __builtin_amdgcn_exp2f(aB[r] * SCL2);
        }
    }
#pragma unroll
    for (int r = 0; r < 4; r++) {
#pragma unroll
        for (int off = 1; off < 16; off <<= 1) {
            sA[r] += __shfl_xor(sA[r], off);
            sB[r] += __shfl_xor(sB[r], off);
        }
    }
    if (arow == 0) {
#pragma unroll
        for (int r = 0; r < 4; r++) {
            wsum[w][agrp * 4 + r] = sA[r];
            wsum[w][16 + agrp * 4 + r] = sB[r];
        }
    }
    __syncthreads();
    if (t < 32)
        rowsumpart[(size_t)sp * NROWS + (size_t)b * SEQ + qbase + t] =
            wsum[0][t] + wsum[1][t];
}

// ---------------------------------------------------------------------------
// Kernel 2b: lr = -log2(sum of partials). (amdgcn logf IS log2.)
// ---------------------------------------------------------------------------
__global__ __launch_bounds__(256) void lr_kernel(
    const float* __restrict__ part, float* __restrict__ lr_g) {
    int i = blockIdx.x * 256 + threadIdx.x;
    float S = part[i] + part[NROWS + i] + part[2 * NROWS + i] + part[3 * NROWS + i];
    lr_g[i] = -__builtin_amdgcn_logf(S);
}

// ---------------------------------------------------------------------------
// Kernel 2c (MERGED attn2+ctx): normalize + write attn + PV + direct ctx.
// One WG = 32 q-rows x ALL 2048 keys: 8 waves, wave w covers keys
// [w*256,(w+1)*256). After PV, 8 wave-partials are reduced through LDS and
// ctx written directly. grid 512 = (qt 64, b 8), b in low 3 bits (XCD pin).
// block 512. LDS sf[8][32][68] = 70 KB -> 2 WG/CU (16 waves/CU).
// ---------------------------------------------------------------------------
__global__ __launch_bounds__(512, 2) void attn2_kernel(
    const unsigned short* __restrict__ qb, const unsigned short* __restrict__ kb,
    const unsigned short* __restrict__ vT, const float* __restrict__ lr_g,
    float* __restrict__ attn_out, float* __restrict__ ctx_out) {
    int blk = blockIdx.x;
    int b = blk & 7;
    int qbase = (blk >> 3) * 32;

    __shared__ float sf[8][32][68];
    __shared__ float lr_lds[32];

    int t = threadIdx.x;
    int lane = t & 63;
    int w = t >> 6;       // 0..7
    int arow = lane & 15;
    int agrp = lane >> 4;

    if (t < 32) lr_lds[t] = lr_g[(size_t)b * SEQ + qbase + t];

    const unsigned short* qrow = qb + ((size_t)b * SEQ + qbase) * AD;
    short8 qf0a = *reinterpret_cast<const short8*>(qrow + (size_t)arow * AD + agrp * 8);
    short8 qf1a = *reinterpret_cast<const short8*>(qrow + (size_t)arow * AD + 32 + agrp * 8);
    short8 qf0b = *reinterpret_cast<const short8*>(qrow + (size_t)(16 + arow) * AD + agrp * 8);
    short8 qf1b = *reinterpret_cast<const short8*>(qrow + (size_t)(16 + arow) * AD + 32 + agrp * 8);
    const unsigned short* kbp = kb + (size_t)b * SEQ * AD;
    const unsigned short* vTb = vT + (size_t)b * AD * SEQ;
    float* attn_b = attn_out + ((size_t)b * SEQ + qbase) * SEQ;
    __syncthreads();

    float lrA[4], lrB[4];
#pragma unroll
    for (int r = 0; r < 4; r++) {
        lrA[r] = lr_lds[agrp * 4 + r];
        lrB[r] = lr_lds[16 + agrp * 4 + r];
    }

    f32x4 caccA[4], caccB[4];
#pragma unroll
    for (int ct = 0; ct < 4; ct++) {
        caccA[ct] = (f32x4){0.f, 0.f, 0.f, 0.f};
        caccB[ct] = (f32x4){0.f, 0.f, 0.f, 0.f};
    }

    int keybase = w * 256;
    for (int g = 0; g < 4; ++g) {
        int key0b = keybase + g * 64;
#pragma unroll
        for (int kb4 = 0; kb4 < 4; ++kb4) {
            int k0 = key0b + kb4 * 16;
            const unsigned short* krow = kbp + (size_t)(k0 + arow) * AD;
            short8 kf0 = *reinterpret_cast<const short8*>(krow + agrp * 8);
            short8 kf1 = *reinterpret_cast<const short8*>(krow + 32 + agrp * 8);
            f32x4 aA = (f32x4){0.f, 0.f, 0.f, 0.f};
            aA = mfma16(qf0a, kf0, aA);
            aA = mfma16(qf1a, kf1, aA);
            f32x4 aB = (f32x4){0.f, 0.f, 0.f, 0.f};
            aB = mfma16(qf0b, kf0, aB);
            aB = mfma16(qf1b, kf1, aB);
#pragma unroll
            for (int r = 0; r < 4; r++) {
                sf[w][agrp * 4 + r][kb4 * 16 + arow] =
                    __builtin_amdgcn_exp2f(aA[r] * SCL2 + lrA[r]);
                sf[w][16 + agrp * 4 + r][kb4 * 16 + arow] =
                    __builtin_amdgcn_exp2f(aB[r] * SCL2 + lrB[r]);
            }
        }
        // coalesced attn stores: 32 rows x 64 keys, 16 B/lane per store
#pragma unroll
        for (int j = 0; j < 8; ++j) {
            int row = j * 4 + agrp;
            int c4 = arow * 4;
            f32x4 vv = *reinterpret_cast<const f32x4*>(&sf[w][row][c4]);
            __builtin_nontemporal_store(
                vv, reinterpret_cast<f32x4*>(&attn_b[(size_t)row * SEQ + key0b + c4]));
        }
        // PV: A-frags from sf (both q-groups), V-frag loaded once, used twice
#pragma unroll
        for (int ks = 0; ks < 2; ++ks) {
            f32x4 pa0 = *reinterpret_cast<const f32x4*>(&sf[w][arow][ks * 32 + agrp * 8]);
            f32x4 pa1 = *reinterpret_cast<const f32x4*>(&sf[w][arow][ks * 32 + agrp * 8 + 4]);
            short8 pfA = pack8v(pa0, pa1);
            f32x4 pb0 = *reinterpret_cast<const f32x4*>(&sf[w][16 + arow][ks * 32 + agrp * 8]);
            f32x4 pb1 = *reinterpret_cast<const f32x4*>(&sf[w][16 + arow][ks * 32 + agrp * 8 + 4]);
            short8 pfB = pack8v(pb0, pb1);
#pragma unroll
            for (int ct = 0; ct < 4; ct++) {
                const unsigned short* vr =
                    vTb + (size_t)(ct * 16 + arow) * SEQ + key0b + ks * 32 + agrp * 8;
                short8 vv = *reinterpret_cast<const short8*>(vr);
                caccA[ct] = mfma16(pfA, vv, caccA[ct]);
                caccB[ct] = mfma16(pfB, vv, caccB[ct]);
            }
        }
    }

    // ---- 8-wave ctx reduce via LDS, then direct ctx write ----
    __syncthreads();  // all waves done with their sf score slices
#pragma unroll
    for (int ct = 0; ct < 4; ct++)
#pragma unroll
        for (int r = 0; r < 4; r++) {
            sf[w][agrp * 4 + r][ct * 16 + arow] = caccA[ct][r];
            sf[w][16 + agrp * 4 + r][ct * 16 + arow] = caccB[ct][r];
        }
    __syncthreads();

    float* ctx_b = ctx_out + ((size_t)b * SEQ + qbase) * AD;
    for (int i = t; i < 32 * 64; i += 512) {
        int r = i >> 6, a = i & 63;
        float v = ((sf[0][r][a] + sf[1][r][a]) + (sf[2][r][a] + sf[3][r][a])) +
                  ((sf[4][r][a] + sf[5][r][a]) + (sf[6][r][a] + sf[7][r][a]));
        __builtin_nontemporal_store(v, &ctx_b[(size_t)r * AD + a]);
    }
}

// ---------------------------------------------------------------------------
extern "C" void kernel_launch(void* const* d_in, const int* in_sizes, int n_in,
                              void* d_out, int out_size, void* d_ws, size_t ws_size,
                              hipStream_t stream) {
    const float* q_in = (const float*)d_in[0];
    const float* k_in = (const float*)d_in[1];
    const float* v_in = (const float*)d_in[2];
    const float* Wq = (const float*)d_in[3];
    const float* bq = (const float*)d_in[4];
    const float* Wk = (const float*)d_in[5];
    const float* bk = (const float*)d_in[6];
    const float* Wv = (const float*)d_in[7];
    const float* bv = (const float*)d_in[8];

    char* ws = (char*)d_ws;
    unsigned short* q_bf = (unsigned short*)(ws);                    // 2 MB
    unsigned short* k_bf = (unsigned short*)(ws + (2u << 20));       // 2 MB
    unsigned short* vT   = (unsigned short*)(ws + (4u << 20));       // 2 MB
    unsigned short* wT   = (unsigned short*)(ws + (6u << 20));       // 384 KB
    float* rowsumpart    = (float*)(ws + (7u << 20));                // 256 KB
    float* lr_g          = (float*)(ws + (7u << 20) + (256u << 10)); // 64 KB

    float* ctx_out = (float*)d_out;
    float* attn_out = ctx_out + (size_t)NB * SEQ * AD;

    hipLaunchKernelGGL(wT_kernel, dim3(16, 3), dim3(256), 0, stream, Wq, Wk, Wv, wT);
    hipLaunchKernelGGL(proj_kernel, dim3(256, 3), dim3(256), 0, stream,
                       q_in, k_in, v_in, bq, bk, bv, wT, q_bf, k_bf, vT);
    hipLaunchKernelGGL(sum_kernel, dim3(2048), dim3(128), 0, stream,
                       q_bf, k_bf, rowsumpart);
    hipLaunchKernelGGL(lr_kernel, dim3(64), dim3(256), 0, stream, rowsumpart, lr_g);
    hipLaunchKernelGGL(attn2_kernel, dim3(512), dim3(512), 0, stream,
                       q_bf, k_bf, vT, lr_g, attn_out, ctx_out);
}

// Round 18
// 101.175 us; speedup vs baseline: 1.4138x; 1.3115x over previous
//
#include <hip/hip_runtime.h>
#include <hip/hip_bf16.h>

#define NB 8
#define SEQ 2048
#define DM 1024
#define AD 64
#define NROWS (NB * SEQ)          // 16384

// exp(s/32) = 2^(s * 0.03125 * log2(e));  log2(e)/32 = 0.045084220
#define SCL2 0.04508422f

typedef __attribute__((ext_vector_type(8))) short short8;
typedef __attribute__((ext_vector_type(4))) float f32x4;

static __device__ __forceinline__ unsigned short f2bf(float f) {
    unsigned int u = __float_as_uint(f);
    u += 0x7FFFu + ((u >> 16) & 1u);
    return (unsigned short)(u >> 16);
}

static __device__ __forceinline__ f32x4 mfma16(short8 a, short8 b, f32x4 c) {
    return __builtin_amdgcn_mfma_f32_16x16x32_bf16(a, b, c, 0, 0, 0);
}

static __device__ __forceinline__ short8 pack8v(f32x4 a, f32x4 b) {
    short8 r;
    r[0] = (short)f2bf(a[0]); r[1] = (short)f2bf(a[1]);
    r[2] = (short)f2bf(a[2]); r[3] = (short)f2bf(a[3]);
    r[4] = (short)f2bf(b[0]); r[5] = (short)f2bf(b[1]);
    r[6] = (short)f2bf(b[2]); r[7] = (short)f2bf(b[3]);
    return r;
}

// ---------------------------------------------------------------------------
// Kernel 0: transpose + convert W (fp32 [1024][64]) -> wT bf16 [3][64][1024]
// ---------------------------------------------------------------------------
__global__ __launch_bounds__(256) void wT_kernel(
    const float* __restrict__ Wq, const float* __restrict__ Wk,
    const float* __restrict__ Wv, unsigned short* __restrict__ wT) {
    int p = blockIdx.y;
    int k0 = blockIdx.x * 64;
    const float* W = (p == 0) ? Wq : (p == 1) ? Wk : Wv;
    __shared__ unsigned short tl[64][72];
    int t = threadIdx.x;
    int c = t & 63;
    int r0 = t >> 6;
    for (int i = 0; i < 16; i++) {
        int k = r0 + i * 4;
        tl[c][k] = f2bf(W[(size_t)(k0 + k) * AD + c]);
    }
    __syncthreads();
    for (int i = 0; i < 16; i++) {
        int a = r0 + i * 4;
        wT[((size_t)p * AD + a) * DM + k0 + c] = tl[a][c];
    }
}

// ---------------------------------------------------------------------------
// Kernel 1: projection X[16384][1024] @ W[1024][64] + b -> bf16.
// R11 STRUCTURE VERBATIM (best direct-measured proj across 14 variants:
// 79 us). Register-staged async-split double-buffered pipeline, X AND W both
// staged (r17 showed direct-W global reads in the compute phase regress to
// 90 us). Padded LDS, no swizzle. __launch_bounds__(256,2).
// grid (256, 3), block 256 (wave w owns rows w*16..w*16+15 of 64-row tile).
// ---------------------------------------------------------------------------
__global__ __launch_bounds__(256, 2) void proj_kernel(
    const float* __restrict__ q_in, const float* __restrict__ k_in,
    const float* __restrict__ v_in, const float* __restrict__ bq,
    const float* __restrict__ bk, const float* __restrict__ bv,
    const unsigned short* __restrict__ wT,
    unsigned short* __restrict__ q_out, unsigned short* __restrict__ k_out,
    unsigned short* __restrict__ vT_out) {
    int p = blockIdx.y;
    int rbase = blockIdx.x * 64;
    const float* X = (p == 0) ? q_in : (p == 1) ? k_in : v_in;
    const float* bias = (p == 0) ? bq : (p == 1) ? bk : bv;
    const unsigned short* wTp = wT + (size_t)p * AD * DM;

    __shared__ float xs[2][64][68];            // fp32 X chunk, pad 4
    __shared__ unsigned short wsm[2][64][72];  // bf16 W chunk, pad 8

    int t = threadIdx.x;
    int lane = t & 63;
    int w = t >> 6;
    int arow = lane & 15;
    int agrp = lane >> 4;

    int srow = t >> 4;        // 0..15
    int scol = (t & 15) * 4;  // fp32 col
    int wrow = t >> 2;        // 0..63
    int wcol = (t & 3) * 16;  // bf16 col

    const float* Xb = X + (size_t)rbase * DM;

    f32x4 acc[4];
#pragma unroll
    for (int ct = 0; ct < 4; ct++) acc[ct] = (f32x4){0.f, 0.f, 0.f, 0.f};

    float4 px0, px1, px2, px3;
    float4 pw0, pw1;

    // prologue: load + write chunk 0
    px0 = *reinterpret_cast<const float4*>(&Xb[(size_t)(0 * 16 + srow) * DM + scol]);
    px1 = *reinterpret_cast<const float4*>(&Xb[(size_t)(1 * 16 + srow) * DM + scol]);
    px2 = *reinterpret_cast<const float4*>(&Xb[(size_t)(2 * 16 + srow) * DM + scol]);
    px3 = *reinterpret_cast<const float4*>(&Xb[(size_t)(3 * 16 + srow) * DM + scol]);
    {
        const char* wp = reinterpret_cast<const char*>(wTp + (size_t)wrow * DM + wcol);
        pw0 = *reinterpret_cast<const float4*>(wp);
        pw1 = *reinterpret_cast<const float4*>(wp + 16);
    }
    *reinterpret_cast<float4*>(&xs[0][0 * 16 + srow][scol]) = px0;
    *reinterpret_cast<float4*>(&xs[0][1 * 16 + srow][scol]) = px1;
    *reinterpret_cast<float4*>(&xs[0][2 * 16 + srow][scol]) = px2;
    *reinterpret_cast<float4*>(&xs[0][3 * 16 + srow][scol]) = px3;
    *reinterpret_cast<float4*>(&wsm[0][wrow][wcol]) = pw0;
    *reinterpret_cast<float4*>(&wsm[0][wrow][wcol + 8]) = pw1;
    __syncthreads();

    for (int c = 0; c < 16; ++c) {
        int bu = c & 1;
        if (c < 15) {
            int kb = (c + 1) * 64;
            px0 = *reinterpret_cast<const float4*>(&Xb[(size_t)(0 * 16 + srow) * DM + kb + scol]);
            px1 = *reinterpret_cast<const float4*>(&Xb[(size_t)(1 * 16 + srow) * DM + kb + scol]);
            px2 = *reinterpret_cast<const float4*>(&Xb[(size_t)(2 * 16 + srow) * DM + kb + scol]);
            px3 = *reinterpret_cast<const float4*>(&Xb[(size_t)(3 * 16 + srow) * DM + kb + scol]);
            const char* wp = reinterpret_cast<const char*>(wTp + (size_t)wrow * DM + kb + wcol);
            pw0 = *reinterpret_cast<const float4*>(wp);
            pw1 = *reinterpret_cast<const float4*>(wp + 16);
        }
        // ---- compute chunk c from LDS ----
        const float* xr = &xs[bu][w * 16 + arow][0];
#pragma unroll
        for (int s = 0; s < 2; ++s) {
            f32x4 a0 = *reinterpret_cast<const f32x4*>(&xr[s * 32 + agrp * 8]);
            f32x4 a1 = *reinterpret_cast<const f32x4*>(&xr[s * 32 + agrp * 8 + 4]);
            short8 af = pack8v(a0, a1);
#pragma unroll
            for (int ct = 0; ct < 4; ++ct) {
                short8 bf = *reinterpret_cast<const short8*>(
                    &wsm[bu][ct * 16 + arow][s * 32 + agrp * 8]);
                acc[ct] = mfma16(af, bf, acc[ct]);
            }
        }
        // ---- write prefetched chunk c+1 (vmcnt wait lands here) ----
        if (c < 15) {
            int bo = bu ^ 1;
            *reinterpret_cast<float4*>(&xs[bo][0 * 16 + srow][scol]) = px0;
            *reinterpret_cast<float4*>(&xs[bo][1 * 16 + srow][scol]) = px1;
            *reinterpret_cast<float4*>(&xs[bo][2 * 16 + srow][scol]) = px2;
            *reinterpret_cast<float4*>(&xs[bo][3 * 16 + srow][scol]) = px3;
            *reinterpret_cast<float4*>(&wsm[bo][wrow][wcol]) = pw0;
            *reinterpret_cast<float4*>(&wsm[bo][wrow][wcol + 8]) = pw1;
        }
        __syncthreads();
    }

    if (p < 2) {
        unsigned short* outp = (p == 0) ? q_out : k_out;
#pragma unroll
        for (int ct = 0; ct < 4; ct++) {
            int a = ct * 16 + arow;
            float bv_ = bias[a];
#pragma unroll
            for (int rr = 0; rr < 4; rr++) {
                int row = rbase + w * 16 + agrp * 4 + rr;
                outp[(size_t)row * AD + a] = f2bf(acc[ct][rr] + bv_);
            }
        }
    } else {
        // transpose via LDS scratch (reuse xs), then write vT[b][a][s]
        unsigned short* sc = (unsigned short*)&xs[0][0][0];  // [64][72]
#pragma unroll
        for (int ct = 0; ct < 4; ct++) {
            int a = ct * 16 + arow;
            float bv_ = bias[a];
#pragma unroll
            for (int rr = 0; rr < 4; rr++) {
                int row = w * 16 + agrp * 4 + rr;
                sc[a * 72 + row] = f2bf(acc[ct][rr] + bv_);
            }
        }
        __syncthreads();
        int bidx = rbase >> 11;
        int sbase = rbase & 2047;
        int rr = t & 63;
        for (int i = 0; i < 16; i++) {
            int a = (t >> 6) + i * 4;
            vT_out[((size_t)bidx * AD + a) * SEQ + sbase + rr] = sc[a * 72 + rr];
        }
    }
}

// ---------------------------------------------------------------------------
// Kernel 2 (FULLY FUSED attention): Phase A computes the softmax denominator
// in-block (wave w sums exp over its 256 keys with Q-frags already in regs;
// 8 wave-partials reduce through 1 KB LDS; lanes 0-31 compute lr = -log2(S)),
// then Phase B normalizes, writes attn (coalesced, nontemporal), PV-MFMAs,
// and reduces ctx across the 8 waves. Replaces sum_kernel + lr_kernel +
// rowsumpart/lr_g round-trips (pure traffic/launch savings, no new pattern).
// grid 512 = (qt 64, b 8), b in low 3 bits (XCD pin). block 512.
// LDS sf[8][32][68] + wsum + lr = ~71 KB -> 2 WG/CU (16 waves/CU).
// ---------------------------------------------------------------------------
__global__ __launch_bounds__(512, 2) void attn2_kernel(
    const unsigned short* __restrict__ qb, const unsigned short* __restrict__ kb,
    const unsigned short* __restrict__ vT, float* __restrict__ attn_out,
    float* __restrict__ ctx_out) {
    int blk = blockIdx.x;
    int b = blk & 7;
    int qbase = (blk >> 3) * 32;

    __shared__ float sf[8][32][68];
    __shared__ float wsum[8][32];
    __shared__ float lr_lds[32];

    int t = threadIdx.x;
    int lane = t & 63;
    int w = t >> 6;       // 0..7
    int arow = lane & 15;
    int agrp = lane >> 4;

    const unsigned short* qrow = qb + ((size_t)b * SEQ + qbase) * AD;
    short8 qf0a = *reinterpret_cast<const short8*>(qrow + (size_t)arow * AD + agrp * 8);
    short8 qf1a = *reinterpret_cast<const short8*>(qrow + (size_t)arow * AD + 32 + agrp * 8);
    short8 qf0b = *reinterpret_cast<const short8*>(qrow + (size_t)(16 + arow) * AD + agrp * 8);
    short8 qf1b = *reinterpret_cast<const short8*>(qrow + (size_t)(16 + arow) * AD + 32 + agrp * 8);
    const unsigned short* kbp = kb + (size_t)b * SEQ * AD;
    const unsigned short* vTb = vT + (size_t)b * AD * SEQ;
    float* attn_b = attn_out + ((size_t)b * SEQ + qbase) * SEQ;

    int keybase = w * 256;

    // ---- Phase A: per-wave exp-sums over its 256 keys (no max needed:
    //      |s| <= ~4, fp32-safe), then 8-wave LDS reduce -> lr ----
    float sA[4] = {0.f, 0.f, 0.f, 0.f};
    float sB[4] = {0.f, 0.f, 0.f, 0.f};
    for (int kt = 0; kt < 16; ++kt) {
        int key0 = keybase + kt * 16;
        const unsigned short* krow = kbp + (size_t)(key0 + arow) * AD;
        short8 kf0 = *reinterpret_cast<const short8*>(krow + agrp * 8);
        short8 kf1 = *reinterpret_cast<const short8*>(krow + 32 + agrp * 8);
        f32x4 aA = (f32x4){0.f, 0.f, 0.f, 0.f};
        aA = mfma16(qf0a, kf0, aA);
        aA = mfma16(qf1a, kf1, aA);
        f32x4 aB = (f32x4){0.f, 0.f, 0.f, 0.f};
        aB = mfma16(qf0b, kf0, aB);
        aB = mfma16(qf1b, kf1, aB);
#pragma unroll
        for (int r = 0; r < 4; r++) {
            sA[r] += __builtin_amdgcn_exp2f(aA[r] * SCL2);
            sB[r] += __builtin_amdgcn_exp2f(aB[r] * SCL2);
        }
    }
#pragma unroll
    for (int r = 0; r < 4; r++) {
#pragma unroll
        for (int off = 1; off < 16; off <<= 1) {
            sA[r] += __shfl_xor(sA[r], off);
            sB[r] += __shfl_xor(sB[r], off);
        }
    }
    if (arow == 0) {
#pragma unroll
        for (int r = 0; r < 4; r++) {
            wsum[w][agrp * 4 + r] = sA[r];
            wsum[w][16 + agrp * 4 + r] = sB[r];
        }
    }
    __syncthreads();
    if (t < 32) {
        float S = ((wsum[0][t] + wsum[1][t]) + (wsum[2][t] + wsum[3][t])) +
                  ((wsum[4][t] + wsum[5][t]) + (wsum[6][t] + wsum[7][t]));
        lr_lds[t] = -__builtin_amdgcn_logf(S);  // amdgcn logf IS log2
    }
    __syncthreads();

    float lrA[4], lrB[4];
#pragma unroll
    for (int r = 0; r < 4; r++) {
        lrA[r] = lr_lds[agrp * 4 + r];
        lrB[r] = lr_lds[16 + agrp * 4 + r];
    }

    // ---- Phase B: recompute QK^T, normalize, write attn, PV ----
    f32x4 caccA[4], caccB[4];
#pragma unroll
    for (int ct = 0; ct < 4; ct++) {
        caccA[ct] = (f32x4){0.f, 0.f, 0.f, 0.f};
        caccB[ct] = (f32x4){0.f, 0.f, 0.f, 0.f};
    }

    for (int g = 0; g < 4; ++g) {
        int key0b = keybase + g * 64;
#pragma unroll
        for (int kb4 = 0; kb4 < 4; ++kb4) {
            int k0 = key0b + kb4 * 16;
            const unsigned short* krow = kbp + (size_t)(k0 + arow) * AD;
            short8 kf0 = *reinterpret_cast<const short8*>(krow + agrp * 8);
            short8 kf1 = *reinterpret_cast<const short8*>(krow + 32 + agrp * 8);
            f32x4 aA = (f32x4){0.f, 0.f, 0.f, 0.f};
            aA = mfma16(qf0a, kf0, aA);
            aA = mfma16(qf1a, kf1, aA);
            f32x4 aB = (f32x4){0.f, 0.f, 0.f, 0.f};
            aB = mfma16(qf0b, kf0, aB);
            aB = mfma16(qf1b, kf1, aB);
#pragma unroll
            for (int r = 0; r < 4; r++) {
                sf[w][agrp * 4 + r][kb4 * 16 + arow] =
                    __builtin_amdgcn_exp2f(aA[r] * SCL2 + lrA[r]);
                sf[w][16 + agrp * 4 + r][kb4 * 16 + arow] =
                    __builtin_amdgcn_exp2f(aB[r] * SCL2 + lrB[r]);
            }
        }
        // coalesced attn stores: 32 rows x 64 keys, 16 B/lane per store
#pragma unroll
        for (int j = 0; j < 8; ++j) {
            int row = j * 4 + agrp;
            int c4 = arow * 4;
            f32x4 vv = *reinterpret_cast<const f32x4*>(&sf[w][row][c4]);
            __builtin_nontemporal_store(
                vv, reinterpret_cast<f32x4*>(&attn_b[(size_t)row * SEQ + key0b + c4]));
        }
        // PV: A-frags from sf (both q-groups), V-frag loaded once, used twice
#pragma unroll
        for (int ks = 0; ks < 2; ++ks) {
            f32x4 pa0 = *reinterpret_cast<const f32x4*>(&sf[w][arow][ks * 32 + agrp * 8]);
            f32x4 pa1 = *reinterpret_cast<const f32x4*>(&sf[w][arow][ks * 32 + agrp * 8 + 4]);
            short8 pfA = pack8v(pa0, pa1);
            f32x4 pb0 = *reinterpret_cast<const f32x4*>(&sf[w][16 + arow][ks * 32 + agrp * 8]);
            f32x4 pb1 = *reinterpret_cast<const f32x4*>(&sf[w][16 + arow][ks * 32 + agrp * 8 + 4]);
            short8 pfB = pack8v(pb0, pb1);
#pragma unroll
            for (int ct = 0; ct < 4; ct++) {
                const unsigned short* vr =
                    vTb + (size_t)(ct * 16 + arow) * SEQ + key0b + ks * 32 + agrp * 8;
                short8 vv = *reinterpret_cast<const short8*>(vr);
                caccA[ct] = mfma16(pfA, vv, caccA[ct]);
                caccB[ct] = mfma16(pfB, vv, caccB[ct]);
            }
        }
    }

    // ---- 8-wave ctx reduce via LDS, then direct ctx write ----
    __syncthreads();  // all waves done with their sf score slices
#pragma unroll
    for (int ct = 0; ct < 4; ct++)
#pragma unroll
        for (int r = 0; r < 4; r++) {
            sf[w][agrp * 4 + r][ct * 16 + arow] = caccA[ct][r];
            sf[w][16 + agrp * 4 + r][ct * 16 + arow] = caccB[ct][r];
        }
    __syncthreads();

    float* ctx_b = ctx_out + ((size_t)b * SEQ + qbase) * AD;
    for (int i = t; i < 32 * 64; i += 512) {
        int r = i >> 6, a = i & 63;
        float v = ((sf[0][r][a] + sf[1][r][a]) + (sf[2][r][a] + sf[3][r][a])) +
                  ((sf[4][r][a] + sf[5][r][a]) + (sf[6][r][a] + sf[7][r][a]));
        __builtin_nontemporal_store(v, &ctx_b[(size_t)r * AD + a]);
    }
}

// ---------------------------------------------------------------------------
extern "C" void kernel_launch(void* const* d_in, const int* in_sizes, int n_in,
                              void* d_out, int out_size, void* d_ws, size_t ws_size,
                              hipStream_t stream) {
    const float* q_in = (const float*)d_in[0];
    const float* k_in = (const float*)d_in[1];
    const float* v_in = (const float*)d_in[2];
    const float* Wq = (const float*)d_in[3];
    const float* bq = (const float*)d_in[4];
    const float* Wk = (const float*)d_in[5];
    const float* bk = (const float*)d_in[6];
    const float* Wv = (const float*)d_in[7];
    const float* bv = (const float*)d_in[8];

    char* ws = (char*)d_ws;
    unsigned short* q_bf = (unsigned short*)(ws);                    // 2 MB
    unsigned short* k_bf = (unsigned short*)(ws + (2u << 20));       // 2 MB
    unsigned short* vT   = (unsigned short*)(ws + (4u << 20));       // 2 MB
    unsigned short* wT   = (unsigned short*)(ws + (6u << 20));       // 384 KB

    float* ctx_out = (float*)d_out;
    float* attn_out = ctx_out + (size_t)NB * SEQ * AD;

    hipLaunchKernelGGL(wT_kernel, dim3(16, 3), dim3(256), 0, stream, Wq, Wk, Wv, wT);
    hipLaunchKernelGGL(proj_kernel, dim3(256, 3), dim3(256), 0, stream,
                       q_in, k_in, v_in, bq, bk, bv, wT, q_bf, k_bf, vT);
    hipLaunchKernelGGL(attn2_kernel, dim3(512), dim3(512), 0, stream,
                       q_bf, k_bf, vT, attn_out, ctx_out);
}